// Round 7
// baseline (836.772 us; speedup 1.0000x reference)
//
#include <hip/hip_runtime.h>
#include <stdint.h>

#define BB 16
#define NN 4096
#define CC 64
#define NPOINT 1024
#define KK 32
#define F1 64
#define F2 64
#define F3 128

#define FPS_T 512
#define PPT (NN / FPS_T)   // 8 points/thread = 4 float2 pairs

typedef float v2f __attribute__((ext_vector_type(2)));

// ---------------- DPP 64-lane max-reduce helpers ----------------
#if defined(__has_builtin)
#if __has_builtin(__builtin_amdgcn_update_dpp)
#define HAS_DPP 1
#endif
#endif

#ifdef HAS_DPP
template <int CTRL>
__device__ __forceinline__ unsigned long long dpp_move64(unsigned long long k) {
    int lo = __builtin_amdgcn_update_dpp(0, (int)(unsigned)k,         CTRL, 0xF, 0xF, false);
    int hi = __builtin_amdgcn_update_dpp(0, (int)(unsigned)(k >> 32), CTRL, 0xF, 0xF, false);
    return ((unsigned long long)(unsigned)hi << 32) | (unsigned)lo;
}
__device__ __forceinline__ unsigned long long wave_max_key(unsigned long long key) {
    unsigned long long o;
    o = dpp_move64<0x111>(key); if (o > key) key = o;   // row_shr:1
    o = dpp_move64<0x112>(key); if (o > key) key = o;   // row_shr:2
    o = dpp_move64<0x114>(key); if (o > key) key = o;   // row_shr:4
    o = dpp_move64<0x118>(key); if (o > key) key = o;   // row_shr:8
    o = dpp_move64<0x142>(key); if (o > key) key = o;   // row_bcast15
    o = dpp_move64<0x143>(key); if (o > key) key = o;   // row_bcast31 -> lane63 has max
    return key;
}
#else
__device__ __forceinline__ unsigned long long wave_max_key(unsigned long long key) {
#pragma unroll
    for (int off = 32; off > 0; off >>= 1) {
        unsigned long long o = __shfl_xor(key, off, 64);
        if (o > key) key = o;
    }
    return key;
}
#endif

// shared-memory arena (union of FPS and MLP layouts)
// FPS : xs[4096] ys[4096] zs[4096] (49152) | wred 2x8 u64 @49152 | cbuf 24f @49280
// MLP : gbuf 32x68 @0 (8704) | hbuf 32x64 @8704 (8192) | pmax 8x128 @16896 (4096)
//       cmask 64 u64 @20992 (512) | nbr @21504 (128) | wbuf @21632 (17152) -> 38784
#define SMEM_BYTES 49664   // 160K/49.664K -> 3 blocks/CU

__global__ __launch_bounds__(512)
void fused_kernel(const float* __restrict__ xyz,
                  const float* __restrict__ points,
                  const float* __restrict__ w0, const float* __restrict__ b0,
                  const float* __restrict__ w1, const float* __restrict__ b1,
                  const float* __restrict__ w2, const float* __restrict__ b2,
                  float* __restrict__ out_xyz,
                  float* __restrict__ out_points,
                  int* __restrict__ ctr) {
    __shared__ __align__(16) char smem[SMEM_BYTES];
    const int tid = threadIdx.x;

    if (blockIdx.x < BB) {
        // ================= FPS (blocks 0..15, resident first => no deadlock) ====
        asm volatile("s_setprio 3");   // out-issue co-resident MLP waves
        float* xs = (float*)smem;
        float* ys = xs + NN;
        float* zs = ys + NN;
        unsigned long long (*wred)[FPS_T / 64] =
            (unsigned long long (*)[FPS_T / 64])(smem + 49152);
        float* cbuf = (float*)(smem + 49280);

        const int b = blockIdx.x;
        const int lane = tid & 63, wid = tid >> 6;
        const float* __restrict__ xb = xyz + (size_t)b * (NN * 3);

        // pair j holds points p = tid + (2j+h)*512, h = 0/1
        v2f px2[4], py2[4], pz2[4], dd[4];
#pragma unroll
        for (int j = 0; j < 4; ++j) {
#pragma unroll
            for (int h = 0; h < 2; ++h) {
                int p = tid + (2 * j + h) * FPS_T;
                float x = xb[p * 3 + 0];
                float y = xb[p * 3 + 1];
                float z = xb[p * 3 + 2];
                px2[j][h] = x; py2[j][h] = y; pz2[j][h] = z;
                xs[p] = x; ys[p] = y; zs[p] = z;
            }
            dd[j] = (v2f){1e10f, 1e10f};
        }
        __syncthreads();

        float cx = xs[0], cy = ys[0], cz = zs[0];
        float* xo = out_xyz + (size_t)b * NPOINT * 3;

        for (int i = 0; i < NPOINT; ++i) {
            if (tid == 0) {             // stage centroid i (LDS only; cheap)
                cbuf[(i & 7) * 3 + 0] = cx;
                cbuf[(i & 7) * 3 + 1] = cy;
                cbuf[(i & 7) * 3 + 2] = cz;
            }
            // ---- packed dist update: v_pk rn-exact, no FMA contraction ----
            {
#pragma clang fp contract(off)
                v2f c2x = (v2f){cx, cx}, c2y = (v2f){cy, cy}, c2z = (v2f){cz, cz};
#pragma unroll
                for (int j = 0; j < 4; ++j) {
                    v2f dx = px2[j] - c2x;
                    v2f dy = py2[j] - c2y;
                    v2f dz = pz2[j] - c2z;
                    v2f ss = (dx * dx + dy * dy) + dz * dz;  // ((x2+y2)+z2), each op rn
                    dd[j] = __builtin_elementwise_min(dd[j], ss);
                }
            }
            // ---- lane-local argmax: packed max + first-occurrence equality scan ----
            v2f m01 = __builtin_elementwise_max(dd[0], dd[1]);
            v2f m23 = __builtin_elementwise_max(dd[2], dd[3]);
            v2f mm  = __builtin_elementwise_max(m01, m23);
            float bd = fmaxf(mm.x, mm.y);
            int bp = 0;
#pragma unroll
            for (int j = 3; j >= 0; --j) {      // descending => smallest t wins
                if (dd[j].y == bd) bp = tid + (2 * j + 1) * FPS_T;
                if (dd[j].x == bd) bp = tid + (2 * j + 0) * FPS_T;
            }
            unsigned long long key = (((unsigned long long)__float_as_uint(bd)) << 32)
                                   | (unsigned int)(NN - 1 - bp);
            key = wave_max_key(key);
            if (lane == 63) wred[i & 1][wid] = key;
            __syncthreads();

            unsigned long long best = wred[i & 1][0];
#pragma unroll
            for (int w = 1; w < FPS_T / 64; ++w) {
                unsigned long long o = wred[i & 1][w];
                if (o > best) best = o;
            }
            int bi = (NN - 1) - (int)(best & 0xffffffffu);

            // publish 8 centroids every 8 iters; drain overlaps next iteration
            if (tid == 0 && (i & 7) == 7) {
                const float4* src = (const float4*)cbuf;
                float4* dst = (float4*)(xo + (size_t)(i - 7) * 3);
                dst[0] = src[0]; dst[1] = src[1]; dst[2] = src[2];
                dst[3] = src[3]; dst[4] = src[4]; dst[5] = src[5];
                __hip_atomic_store(&ctr[b * 16], i + 1,
                                   __ATOMIC_RELEASE, __HIP_MEMORY_SCOPE_AGENT);
            }
            cx = xs[bi]; cy = ys[bi]; cz = zs[bi];
        }
    } else {
        // ================= fused ball query + gather + MLP + maxpool ===========
        float (*gbuf)[68] = (float (*)[68])smem;
        float (*hbuf)[F1] = (float (*)[F1])(smem + 8704);
        float (*pmax)[F3] = (float (*)[F3])(smem + 16896);
        unsigned long long* cmask = (unsigned long long*)(smem + 20992);
        int* nbr = (int*)(smem + 21504);
        float* wbuf = (float*)(smem + 21632);       // 4288 floats max
        float4* wbuf4 = (float4*)wbuf;

        const int gi = blockIdx.x - BB;
        const int s = gi >> 4;          // s-major: early blocks need early centroids
        const int b = gi & 15;
        const int g = b * NPOINT + s;
        const int f = tid & 63;
        const int wid = tid >> 6;       // 0..7

        // ---- stage w0 into LDS (overlaps the centroid spin-wait) ----
        {
            const float4* src = (const float4*)w0;
#pragma unroll
            for (int i = tid; i < 1072; i += 512) wbuf4[i] = src[i];
        }

        // wait until centroid s is published (poison 0xAAAAAAAA < 0 => waits)
        if (tid == 0) {
            while (__hip_atomic_load(&ctr[b * 16], __ATOMIC_RELAXED,
                                     __HIP_MEMORY_SCOPE_AGENT) < s + 1)
                __builtin_amdgcn_s_sleep(2);
            (void)__hip_atomic_load(&ctr[b * 16], __ATOMIC_ACQUIRE,
                                    __HIP_MEMORY_SCOPE_AGENT);
        }
        __syncthreads();

        // centroid via agent-scope loads (LLC-direct; immune to stale per-XCD L2)
        unsigned int ux = __hip_atomic_load((unsigned int*)&out_xyz[(size_t)g * 3 + 0],
                                            __ATOMIC_RELAXED, __HIP_MEMORY_SCOPE_AGENT);
        unsigned int uy = __hip_atomic_load((unsigned int*)&out_xyz[(size_t)g * 3 + 1],
                                            __ATOMIC_RELAXED, __HIP_MEMORY_SCOPE_AGENT);
        unsigned int uz = __hip_atomic_load((unsigned int*)&out_xyz[(size_t)g * 3 + 2],
                                            __ATOMIC_RELAXED, __HIP_MEMORY_SCOPE_AGENT);
        const float cx = __uint_as_float(ux);
        const float cy = __uint_as_float(uy);
        const float cz = __uint_as_float(uz);

        // ---- phase A1: 8 waves scan all 4096 points ----
        {
            const float* __restrict__ xb = xyz + (size_t)b * (NN * 3);
#pragma unroll
            for (int j = 0; j < 8; ++j) {
                int chunk = wid * 8 + j;
                int p = chunk * 64 + f;
                float x = xb[p * 3 + 0];
                float y = xb[p * 3 + 1];
                float z = xb[p * 3 + 2];
                float dx = __fsub_rn(cx, x);
                float dy = __fsub_rn(cy, y);
                float dz = __fsub_rn(cz, z);
                float d2 = __fadd_rn(__fadd_rn(__fmul_rn(dx, dx), __fmul_rn(dy, dy)),
                                     __fmul_rn(dz, dz));
                unsigned long long m = __ballot(d2 <= 0.04f);  // float32(0.2*0.2)
                if (f == 0) cmask[chunk] = m;
            }
        }
        __syncthreads();

        // ---- phase A2: wave 0 — ordered compaction of the 32 smallest indices ----
        if (tid < 64) {
            unsigned long long m = cmask[tid];
            int cnt = (int)__popcll(m);
            int v = cnt;
#pragma unroll
            for (int off = 1; off < 64; off <<= 1) {
                int u = __shfl_up(v, off, 64);
                if (tid >= off) v += u;
            }
            int excl = v - cnt;
            int total = __shfl(v, 63, 64);
            unsigned long long mm = m;
            int r = excl;
            while (mm && r < KK) {
                int bpos = __ffsll(mm) - 1;
                mm &= mm - 1;
                nbr[r++] = tid * 64 + bpos;
            }
            if (total < KK) {
                unsigned long long nz = __ballot(cnt > 0);
                int fchunk = __ffsll(nz) - 1;
                unsigned long long fm = cmask[fchunk];
                int first = fchunk * 64 + __ffsll(fm) - 1;
                if (tid >= total && tid < KK) nbr[tid] = first;
            }
        }
        __syncthreads();

        // ---- phase B: gather into LDS ----
        {
            const float* __restrict__ pb = points + (size_t)b * NN * CC;
#pragma unroll
            for (int m = 0; m < 4; ++m) {
                int k = wid + 8 * m;
                int idx = nbr[k] & (NN - 1);
                gbuf[k][f] = pb[(size_t)idx * CC + f];
            }
            if (tid < 96) {
                int k = tid & 31, q = tid >> 5;
                int idx = nbr[k] & (NN - 1);
                float v = xyz[((size_t)b * NN + idx) * 3 + q];
                float cq = (q == 0) ? cx : ((q == 1) ? cy : cz);
                gbuf[k][CC + q] = __fsub_rn(v, cq);
            }
        }
        __syncthreads();

        v2f acc2[4];

        // ---- layer 1: 67 -> 64 (w0 in LDS, packed fma over c-pairs) ----
#pragma unroll
        for (int m = 0; m < 4; ++m) acc2[m] = (v2f){0.0f, 0.0f};
#pragma unroll 4
        for (int c4 = 0; c4 < 64; c4 += 4) {
            v2f w01 = (v2f){wbuf[(c4 + 0) * F1 + f], wbuf[(c4 + 1) * F1 + f]};
            v2f w23 = (v2f){wbuf[(c4 + 2) * F1 + f], wbuf[(c4 + 3) * F1 + f]};
#pragma unroll
            for (int m = 0; m < 4; ++m) {
                float4 gv = *(const float4*)&gbuf[wid + 8 * m][c4];
                acc2[m] = __builtin_elementwise_fma((v2f){gv.x, gv.y}, w01, acc2[m]);
                acc2[m] = __builtin_elementwise_fma((v2f){gv.z, gv.w}, w23, acc2[m]);
            }
        }
        {
            float wv0 = wbuf[64 * F1 + f];
            float wv1 = wbuf[65 * F1 + f];
            float wv2 = wbuf[66 * F1 + f];
            float bb = b0[f];
#pragma unroll
            for (int m = 0; m < 4; ++m) {
                int k = wid + 8 * m;
                float a = acc2[m].x + acc2[m].y;
                a = fmaf(gbuf[k][64], wv0, a);
                a = fmaf(gbuf[k][65], wv1, a);
                a = fmaf(gbuf[k][66], wv2, a);
                hbuf[k][f] = fmaxf(a + bb, 0.0f);
            }
        }
        __syncthreads();

        // ---- stage w1 (overwrites w0 region) ----
        {
            const float4* src = (const float4*)w1;
#pragma unroll
            for (int i = tid; i < 1024; i += 512) wbuf4[i] = src[i];
        }
        __syncthreads();

        // ---- layer 2: 64 -> 64 ----
#pragma unroll
        for (int m = 0; m < 4; ++m) acc2[m] = (v2f){0.0f, 0.0f};
#pragma unroll 4
        for (int c4 = 0; c4 < 64; c4 += 4) {
            v2f w01 = (v2f){wbuf[(c4 + 0) * F2 + f], wbuf[(c4 + 1) * F2 + f]};
            v2f w23 = (v2f){wbuf[(c4 + 2) * F2 + f], wbuf[(c4 + 3) * F2 + f]};
#pragma unroll
            for (int m = 0; m < 4; ++m) {
                float4 gv = *(const float4*)&hbuf[wid + 8 * m][c4];
                acc2[m] = __builtin_elementwise_fma((v2f){gv.x, gv.y}, w01, acc2[m]);
                acc2[m] = __builtin_elementwise_fma((v2f){gv.z, gv.w}, w23, acc2[m]);
            }
        }
        {
            float bb = b1[f];
#pragma unroll
            for (int m = 0; m < 4; ++m)
                gbuf[wid + 8 * m][f] = fmaxf(acc2[m].x + acc2[m].y + bb, 0.0f);
        }
        __syncthreads();

        // ---- layer 3: 64 -> 128 in two output-column halves + maxpool ----
#pragma unroll
        for (int h = 0; h < 2; ++h) {
            // stage w2[:, 64h : 64h+64] (16 KB)
            {
                const float4* src = (const float4*)w2;
#pragma unroll
                for (int i = tid; i < 1024; i += 512) {
                    int c = i >> 4, col4 = i & 15;
                    wbuf4[i] = src[c * 32 + 16 * h + col4];
                }
            }
            __syncthreads();
#pragma unroll
            for (int m = 0; m < 4; ++m) acc2[m] = (v2f){0.0f, 0.0f};
#pragma unroll 4
            for (int c4 = 0; c4 < 64; c4 += 4) {
                v2f w01 = (v2f){wbuf[(c4 + 0) * 64 + f], wbuf[(c4 + 1) * 64 + f]};
                v2f w23 = (v2f){wbuf[(c4 + 2) * 64 + f], wbuf[(c4 + 3) * 64 + f]};
#pragma unroll
                for (int m = 0; m < 4; ++m) {
                    float4 gv = *(const float4*)&gbuf[wid + 8 * m][c4];
                    acc2[m] = __builtin_elementwise_fma((v2f){gv.x, gv.y}, w01, acc2[m]);
                    acc2[m] = __builtin_elementwise_fma((v2f){gv.z, gv.w}, w23, acc2[m]);
                }
            }
            {
                float pm = -1e30f;
#pragma unroll
                for (int m = 0; m < 4; ++m) pm = fmaxf(pm, acc2[m].x + acc2[m].y);
                pmax[wid][f + 64 * h] = pm;
            }
            __syncthreads();   // also guards wbuf overwrite for h=1
        }

        if (tid < F3) {
            float v = pmax[0][tid];
#pragma unroll
            for (int w = 1; w < 8; ++w) v = fmaxf(v, pmax[w][tid]);
            v = fmaxf(v + b2[tid], 0.0f);   // relu(max+b) == max(relu(+b))
            out_points[(size_t)g * F3 + tid] = v;
        }
    }
}

extern "C" void kernel_launch(void* const* d_in, const int* in_sizes, int n_in,
                              void* d_out, int out_size, void* d_ws, size_t ws_size,
                              hipStream_t stream) {
    const float* xyz    = (const float*)d_in[0];
    const float* points = (const float*)d_in[1];
    const float* w0 = (const float*)d_in[2];
    const float* b0 = (const float*)d_in[3];
    const float* w1 = (const float*)d_in[4];
    const float* b1 = (const float*)d_in[5];
    const float* w2 = (const float*)d_in[6];
    const float* b2 = (const float*)d_in[7];

    float* out_xyz    = (float*)d_out;
    float* out_points = out_xyz + (size_t)BB * NPOINT * 3;
    int*   ctr        = (int*)d_ws;   // 16 counters, 64B stride

    fused_kernel<<<BB + BB * NPOINT, 512, 0, stream>>>(
        xyz, points, w0, b0, w1, b1, w2, b2, out_xyz, out_points, ctr);
}

// Round 8
// 820.084 us; speedup vs baseline: 1.0203x; 1.0203x over previous
//
#include <hip/hip_runtime.h>
#include <stdint.h>

#define BB 16
#define NN 4096
#define CC 64
#define NPOINT 1024
#define KK 32
#define F1 64
#define F2 64
#define F3 128

#define FPS_T 512
#define PPT (NN / FPS_T)   // 8 points/thread = 4 float2 pairs

typedef float v2f __attribute__((ext_vector_type(2)));

// ---------------- DPP 64-lane max-reduce helpers ----------------
#if defined(__has_builtin)
#if __has_builtin(__builtin_amdgcn_update_dpp)
#define HAS_DPP 1
#endif
#endif

#ifdef HAS_DPP
template <int CTRL>
__device__ __forceinline__ unsigned long long dpp_move64(unsigned long long k) {
    int lo = __builtin_amdgcn_update_dpp(0, (int)(unsigned)k,         CTRL, 0xF, 0xF, false);
    int hi = __builtin_amdgcn_update_dpp(0, (int)(unsigned)(k >> 32), CTRL, 0xF, 0xF, false);
    return ((unsigned long long)(unsigned)hi << 32) | (unsigned)lo;
}
__device__ __forceinline__ unsigned long long wave_max_key(unsigned long long key) {
    unsigned long long o;
    o = dpp_move64<0x111>(key); if (o > key) key = o;   // row_shr:1
    o = dpp_move64<0x112>(key); if (o > key) key = o;   // row_shr:2
    o = dpp_move64<0x114>(key); if (o > key) key = o;   // row_shr:4
    o = dpp_move64<0x118>(key); if (o > key) key = o;   // row_shr:8
    o = dpp_move64<0x142>(key); if (o > key) key = o;   // row_bcast15
    o = dpp_move64<0x143>(key); if (o > key) key = o;   // row_bcast31 -> lane63 has max
    return key;
}
#else
__device__ __forceinline__ unsigned long long wave_max_key(unsigned long long key) {
#pragma unroll
    for (int off = 32; off > 0; off >>= 1) {
        unsigned long long o = __shfl_xor(key, off, 64);
        if (o > key) key = o;
    }
    return key;
}
#endif

// shared-memory arena (union of FPS and MLP layouts)
// FPS : xs[4096] ys[4096] zs[4096] (49152) | wred 2x8 u64 @49152 | cbuf 96f @49280
// MLP : gbuf 32x68 @0 | hbuf 32x64 @8704 | pmax 8x128 @16896 | cmask @20992 | nbr @21504
#define SMEM_BYTES 49664   // 3 blocks/CU cap (FPS CU hosts at most 2 MLP blocks)

__global__ __launch_bounds__(512)
void fused_kernel(const float* __restrict__ xyz,
                  const float* __restrict__ points,
                  const float* __restrict__ w0, const float* __restrict__ b0,
                  const float* __restrict__ w1, const float* __restrict__ b1,
                  const float* __restrict__ w2, const float* __restrict__ b2,
                  float* __restrict__ out_xyz,
                  float* __restrict__ out_points,
                  int* __restrict__ ctr) {
    __shared__ __align__(16) char smem[SMEM_BYTES];
    const int tid = threadIdx.x;

    if (blockIdx.x < BB) {
        // ================= FPS (blocks 0..15, resident first => no deadlock) ====
        asm volatile("s_setprio 3");   // out-issue co-resident MLP waves
        float* xs = (float*)smem;
        float* ys = xs + NN;
        float* zs = ys + NN;
        unsigned long long (*wred)[FPS_T / 64] =
            (unsigned long long (*)[FPS_T / 64])(smem + 49152);
        float* cbuf = (float*)(smem + 49280);   // 32 centroids staging (96 floats)

        const int b = blockIdx.x;
        const int lane = tid & 63, wid = tid >> 6;
        const float* __restrict__ xb = xyz + (size_t)b * (NN * 3);

        // pair j holds points p = tid + (2j+h)*512, h = 0/1
        v2f px2[4], py2[4], pz2[4], dd[4];
#pragma unroll
        for (int j = 0; j < 4; ++j) {
#pragma unroll
            for (int h = 0; h < 2; ++h) {
                int p = tid + (2 * j + h) * FPS_T;
                float x = xb[p * 3 + 0];
                float y = xb[p * 3 + 1];
                float z = xb[p * 3 + 2];
                px2[j][h] = x; py2[j][h] = y; pz2[j][h] = z;
                xs[p] = x; ys[p] = y; zs[p] = z;
            }
            dd[j] = (v2f){1e10f, 1e10f};
        }
        __syncthreads();

        float cx = xs[0], cy = ys[0], cz = zs[0];
        float* xo = out_xyz + (size_t)b * NPOINT * 3;

        for (int i = 0; i < NPOINT; ++i) {
            if (tid == 0) {             // stage centroid i (LDS only; cheap)
                cbuf[(i & 31) * 3 + 0] = cx;
                cbuf[(i & 31) * 3 + 1] = cy;
                cbuf[(i & 31) * 3 + 2] = cz;
            }
            // ---- packed dist update: v_pk rn-exact, no FMA contraction ----
            {
#pragma clang fp contract(off)
                v2f c2x = (v2f){cx, cx}, c2y = (v2f){cy, cy}, c2z = (v2f){cz, cz};
#pragma unroll
                for (int j = 0; j < 4; ++j) {
                    v2f dx = px2[j] - c2x;
                    v2f dy = py2[j] - c2y;
                    v2f dz = pz2[j] - c2z;
                    v2f ss = (dx * dx + dy * dy) + dz * dz;  // ((x2+y2)+z2), each op rn
                    dd[j] = __builtin_elementwise_min(dd[j], ss);
                }
            }
            // ---- lane-local argmax: packed max + first-occurrence equality scan ----
            v2f m01 = __builtin_elementwise_max(dd[0], dd[1]);
            v2f m23 = __builtin_elementwise_max(dd[2], dd[3]);
            v2f mm  = __builtin_elementwise_max(m01, m23);
            float bd = fmaxf(mm.x, mm.y);
            int bp = 0;
#pragma unroll
            for (int j = 3; j >= 0; --j) {      // descending => smallest t wins
                if (dd[j].y == bd) bp = tid + (2 * j + 1) * FPS_T;
                if (dd[j].x == bd) bp = tid + (2 * j + 0) * FPS_T;
            }
            unsigned long long key = (((unsigned long long)__float_as_uint(bd)) << 32)
                                   | (unsigned int)(NN - 1 - bp);
            key = wave_max_key(key);
            if (lane == 63) wred[i & 1][wid] = key;
            __syncthreads();

            unsigned long long best = wred[i & 1][0];
#pragma unroll
            for (int w = 1; w < FPS_T / 64; ++w) {
                unsigned long long o = wred[i & 1][w];
                if (o > best) best = o;
            }
            int bi = (NN - 1) - (int)(best & 0xffffffffu);

            // publish 32 centroids every 32 iters; vmcnt drain amortized 4x vs R7
            if (tid == 0 && (i & 31) == 31) {
                const float4* src = (const float4*)cbuf;
                float4* dst = (float4*)(xo + (size_t)(i - 31) * 3);
#pragma unroll
                for (int q = 0; q < 24; ++q) dst[q] = src[q];
                __hip_atomic_store(&ctr[b * 16], i + 1,
                                   __ATOMIC_RELEASE, __HIP_MEMORY_SCOPE_AGENT);
            }
            cx = xs[bi]; cy = ys[bi]; cz = zs[bi];
        }
    } else {
        // ================= fused ball query + gather + MLP + maxpool ===========
        // LDS-light on purpose: weights come from global (L2-resident) so the
        // LDS pipe stays free for the co-resident FPS block's critical path.
        float (*gbuf)[68] = (float (*)[68])smem;
        float (*hbuf)[F1] = (float (*)[F1])(smem + 8704);
        float (*pmax)[F3] = (float (*)[F3])(smem + 16896);
        unsigned long long* cmask = (unsigned long long*)(smem + 20992);
        int* nbr = (int*)(smem + 21504);

        const int gi = blockIdx.x - BB;
        const int s = gi >> 4;          // s-major: early blocks need early centroids
        const int b = gi & 15;
        const int g = b * NPOINT + s;
        const int f = tid & 63;
        const int wid = tid >> 6;       // 0..7

        // wait until centroid s is published; adaptive backoff (poison<0 => long)
        if (tid == 0) {
            const int target = s + 1;
            int c;
            while ((c = __hip_atomic_load(&ctr[b * 16], __ATOMIC_RELAXED,
                                          __HIP_MEMORY_SCOPE_AGENT)) < target) {
                if (target - c > 64) __builtin_amdgcn_s_sleep(64);
                else                 __builtin_amdgcn_s_sleep(4);
            }
            (void)__hip_atomic_load(&ctr[b * 16], __ATOMIC_ACQUIRE,
                                    __HIP_MEMORY_SCOPE_AGENT);
        }
        __syncthreads();

        // centroid via agent-scope loads (LLC-direct; immune to stale per-XCD L2)
        unsigned int ux = __hip_atomic_load((unsigned int*)&out_xyz[(size_t)g * 3 + 0],
                                            __ATOMIC_RELAXED, __HIP_MEMORY_SCOPE_AGENT);
        unsigned int uy = __hip_atomic_load((unsigned int*)&out_xyz[(size_t)g * 3 + 1],
                                            __ATOMIC_RELAXED, __HIP_MEMORY_SCOPE_AGENT);
        unsigned int uz = __hip_atomic_load((unsigned int*)&out_xyz[(size_t)g * 3 + 2],
                                            __ATOMIC_RELAXED, __HIP_MEMORY_SCOPE_AGENT);
        const float cx = __uint_as_float(ux);
        const float cy = __uint_as_float(uy);
        const float cz = __uint_as_float(uz);

        // ---- phase A1: 8 waves scan all 4096 points ----
        {
            const float* __restrict__ xb = xyz + (size_t)b * (NN * 3);
#pragma unroll
            for (int j = 0; j < 8; ++j) {
                int chunk = wid * 8 + j;
                int p = chunk * 64 + f;
                float x = xb[p * 3 + 0];
                float y = xb[p * 3 + 1];
                float z = xb[p * 3 + 2];
                float dx = __fsub_rn(cx, x);
                float dy = __fsub_rn(cy, y);
                float dz = __fsub_rn(cz, z);
                float d2 = __fadd_rn(__fadd_rn(__fmul_rn(dx, dx), __fmul_rn(dy, dy)),
                                     __fmul_rn(dz, dz));
                unsigned long long m = __ballot(d2 <= 0.04f);  // float32(0.2*0.2)
                if (f == 0) cmask[chunk] = m;
            }
        }
        __syncthreads();

        // ---- phase A2: wave 0 — ordered compaction of the 32 smallest indices ----
        if (tid < 64) {
            unsigned long long m = cmask[tid];
            int cnt = (int)__popcll(m);
            int v = cnt;
#pragma unroll
            for (int off = 1; off < 64; off <<= 1) {
                int u = __shfl_up(v, off, 64);
                if (tid >= off) v += u;
            }
            int excl = v - cnt;
            int total = __shfl(v, 63, 64);
            unsigned long long mm = m;
            int r = excl;
            while (mm && r < KK) {
                int bpos = __ffsll(mm) - 1;
                mm &= mm - 1;
                nbr[r++] = tid * 64 + bpos;
            }
            if (total < KK) {
                unsigned long long nz = __ballot(cnt > 0);
                int fchunk = __ffsll(nz) - 1;
                unsigned long long fm = cmask[fchunk];
                int first = fchunk * 64 + __ffsll(fm) - 1;
                if (tid >= total && tid < KK) nbr[tid] = first;
            }
        }
        __syncthreads();

        // ---- phase B: gather into LDS ----
        {
            const float* __restrict__ pb = points + (size_t)b * NN * CC;
#pragma unroll
            for (int m = 0; m < 4; ++m) {
                int k = wid + 8 * m;
                int idx = nbr[k] & (NN - 1);
                gbuf[k][f] = pb[(size_t)idx * CC + f];
            }
            if (tid < 96) {
                int k = tid & 31, q = tid >> 5;
                int idx = nbr[k] & (NN - 1);
                float v = xyz[((size_t)b * NN + idx) * 3 + q];
                float cq = (q == 0) ? cx : ((q == 1) ? cy : cz);
                gbuf[k][CC + q] = __fsub_rn(v, cq);
            }
        }
        __syncthreads();

        v2f acc2[4];

        // ---- layer 1: 67 -> 64 (global weights, packed fma over c-pairs) ----
#pragma unroll
        for (int m = 0; m < 4; ++m) acc2[m] = (v2f){0.0f, 0.0f};
#pragma unroll 4
        for (int c4 = 0; c4 < 64; c4 += 4) {
            v2f wA = (v2f){w0[(c4 + 0) * F1 + f], w0[(c4 + 1) * F1 + f]};
            v2f wB = (v2f){w0[(c4 + 2) * F1 + f], w0[(c4 + 3) * F1 + f]};
#pragma unroll
            for (int m = 0; m < 4; ++m) {
                float4 gv = *(const float4*)&gbuf[wid + 8 * m][c4];
                acc2[m] = __builtin_elementwise_fma((v2f){gv.x, gv.y}, wA, acc2[m]);
                acc2[m] = __builtin_elementwise_fma((v2f){gv.z, gv.w}, wB, acc2[m]);
            }
        }
        {
            float wv0 = w0[64 * F1 + f];
            float wv1 = w0[65 * F1 + f];
            float wv2 = w0[66 * F1 + f];
            float bb = b0[f];
#pragma unroll
            for (int m = 0; m < 4; ++m) {
                int k = wid + 8 * m;
                float a = acc2[m].x + acc2[m].y;
                a = fmaf(gbuf[k][64], wv0, a);
                a = fmaf(gbuf[k][65], wv1, a);
                a = fmaf(gbuf[k][66], wv2, a);
                hbuf[k][f] = fmaxf(a + bb, 0.0f);
            }
        }
        __syncthreads();

        // ---- layer 2: 64 -> 64 ----
#pragma unroll
        for (int m = 0; m < 4; ++m) acc2[m] = (v2f){0.0f, 0.0f};
#pragma unroll 4
        for (int c4 = 0; c4 < 64; c4 += 4) {
            v2f wA = (v2f){w1[(c4 + 0) * F2 + f], w1[(c4 + 1) * F2 + f]};
            v2f wB = (v2f){w1[(c4 + 2) * F2 + f], w1[(c4 + 3) * F2 + f]};
#pragma unroll
            for (int m = 0; m < 4; ++m) {
                float4 gv = *(const float4*)&hbuf[wid + 8 * m][c4];
                acc2[m] = __builtin_elementwise_fma((v2f){gv.x, gv.y}, wA, acc2[m]);
                acc2[m] = __builtin_elementwise_fma((v2f){gv.z, gv.w}, wB, acc2[m]);
            }
        }
        {
            float bb = b1[f];
#pragma unroll
            for (int m = 0; m < 4; ++m)
                gbuf[wid + 8 * m][f] = fmaxf(acc2[m].x + acc2[m].y + bb, 0.0f);
        }
        __syncthreads();

        // ---- layer 3: 64 -> 128 + maxpool ----
        v2f a0[4], a1[4];
#pragma unroll
        for (int m = 0; m < 4; ++m) { a0[m] = (v2f){0.f, 0.f}; a1[m] = (v2f){0.f, 0.f}; }
#pragma unroll 2
        for (int c4 = 0; c4 < 64; c4 += 4) {
            v2f wA0 = (v2f){w2[(c4 + 0) * F3 + f],      w2[(c4 + 1) * F3 + f]};
            v2f wB0 = (v2f){w2[(c4 + 2) * F3 + f],      w2[(c4 + 3) * F3 + f]};
            v2f wA1 = (v2f){w2[(c4 + 0) * F3 + f + 64], w2[(c4 + 1) * F3 + f + 64]};
            v2f wB1 = (v2f){w2[(c4 + 2) * F3 + f + 64], w2[(c4 + 3) * F3 + f + 64]};
#pragma unroll
            for (int m = 0; m < 4; ++m) {
                float4 gv = *(const float4*)&gbuf[wid + 8 * m][c4];
                a0[m] = __builtin_elementwise_fma((v2f){gv.x, gv.y}, wA0, a0[m]);
                a0[m] = __builtin_elementwise_fma((v2f){gv.z, gv.w}, wB0, a0[m]);
                a1[m] = __builtin_elementwise_fma((v2f){gv.x, gv.y}, wA1, a1[m]);
                a1[m] = __builtin_elementwise_fma((v2f){gv.z, gv.w}, wB1, a1[m]);
            }
        }
        {
            float pm0 = -1e30f, pm1 = -1e30f;
#pragma unroll
            for (int m = 0; m < 4; ++m) {
                pm0 = fmaxf(pm0, a0[m].x + a0[m].y);
                pm1 = fmaxf(pm1, a1[m].x + a1[m].y);
            }
            pmax[wid][f] = pm0;
            pmax[wid][f + 64] = pm1;
        }
        __syncthreads();
        if (tid < F3) {
            float v = pmax[0][tid];
#pragma unroll
            for (int w = 1; w < 8; ++w) v = fmaxf(v, pmax[w][tid]);
            v = fmaxf(v + b2[tid], 0.0f);   // relu(max+b) == max(relu(+b))
            out_points[(size_t)g * F3 + tid] = v;
        }
    }
}

extern "C" void kernel_launch(void* const* d_in, const int* in_sizes, int n_in,
                              void* d_out, int out_size, void* d_ws, size_t ws_size,
                              hipStream_t stream) {
    const float* xyz    = (const float*)d_in[0];
    const float* points = (const float*)d_in[1];
    const float* w0 = (const float*)d_in[2];
    const float* b0 = (const float*)d_in[3];
    const float* w1 = (const float*)d_in[4];
    const float* b1 = (const float*)d_in[5];
    const float* w2 = (const float*)d_in[6];
    const float* b2 = (const float*)d_in[7];

    float* out_xyz    = (float*)d_out;
    float* out_points = out_xyz + (size_t)BB * NPOINT * 3;
    int*   ctr        = (int*)d_ws;   // 16 counters, 64B stride

    fused_kernel<<<BB + BB * NPOINT, 512, 0, stream>>>(
        xyz, points, w0, b0, w1, b1, w2, b2, out_xyz, out_points, ctr);
}